// Round 1
// baseline (20995.525 us; speedup 1.0000x reference)
//
#include <hip/hip_runtime.h>

#define BB 64
#define TT 1024
#define DD 512
#define BT (BB*TT)

typedef float f4 __attribute__((ext_vector_type(4)));

// ===========================================================================
// GEMM: C[bt, e'] = sum_d x[bt,d] * W[e',d] + bias[e']   (all f32)
// (unchanged — verified absmax 0.0)
// ===========================================================================
__global__ __launch_bounds__(256, 2) void gemm_kernel(
    const float* __restrict__ x, const float* __restrict__ tau_w,
    const float* __restrict__ tau_b, const float* __restrict__ mem_w,
    const float* __restrict__ mem_b, float* __restrict__ xp, float* __restrict__ mm)
{
    __shared__ float As[32][132];
    __shared__ float Bs[32][68];

    const int tid  = threadIdx.x;
    const int bt0  = blockIdx.x * 128;
    const bool isxp = (blockIdx.y < 8);
    const float* W       = isxp ? tau_w : mem_w;
    const int    wstride = isxp ? 1024 : 512;
    const int    e0      = isxp ? blockIdx.y * 64 : blockIdx.y * 64 - 512;
    const float* bias    = isxp ? tau_b : mem_b;
    float*       dst     = isxp ? xp : mm;

    const int tm = tid & 31, tn = tid >> 5;
    const int lr = tid >> 3, lc = tid & 7;

    float bias_r[8];
#pragma unroll
    for (int ni = 0; ni < 8; ni++) bias_r[ni] = bias[e0 + tn * 8 + ni];

    float acc[4][8] = {};
    float4 pa[4], pb[2];

#pragma unroll
    for (int j = 0; j < 4; j++)
        pa[j] = *(const float4*)(x + (size_t)(bt0 + lr + 32 * j) * DD + lc * 4);
#pragma unroll
    for (int j = 0; j < 2; j++)
        pb[j] = *(const float4*)(W + (size_t)(e0 + lr + 32 * j) * wstride + lc * 4);

    for (int kb = 0; kb < DD; kb += 32) {
#pragma unroll
        for (int j = 0; j < 4; j++) {
            As[lc * 4 + 0][lr + 32 * j] = pa[j].x;
            As[lc * 4 + 1][lr + 32 * j] = pa[j].y;
            As[lc * 4 + 2][lr + 32 * j] = pa[j].z;
            As[lc * 4 + 3][lr + 32 * j] = pa[j].w;
        }
#pragma unroll
        for (int j = 0; j < 2; j++) {
            Bs[lc * 4 + 0][lr + 32 * j] = pb[j].x;
            Bs[lc * 4 + 1][lr + 32 * j] = pb[j].y;
            Bs[lc * 4 + 2][lr + 32 * j] = pb[j].z;
            Bs[lc * 4 + 3][lr + 32 * j] = pb[j].w;
        }
        __syncthreads();
        if (kb + 32 < DD) {
#pragma unroll
            for (int j = 0; j < 4; j++)
                pa[j] = *(const float4*)(x + (size_t)(bt0 + lr + 32 * j) * DD + kb + 32 + lc * 4);
#pragma unroll
            for (int j = 0; j < 2; j++)
                pb[j] = *(const float4*)(W + (size_t)(e0 + lr + 32 * j) * wstride + kb + 32 + lc * 4);
        }
#pragma unroll
        for (int k = 0; k < 32; k++) {
            float4 av  = *(const float4*)&As[k][tm * 4];
            float4 bv0 = *(const float4*)&Bs[k][tn * 8];
            float4 bv1 = *(const float4*)&Bs[k][tn * 8 + 4];
            float a_[4] = {av.x, av.y, av.z, av.w};
            float b_[8] = {bv0.x, bv0.y, bv0.z, bv0.w, bv1.x, bv1.y, bv1.z, bv1.w};
#pragma unroll
            for (int mi = 0; mi < 4; mi++)
#pragma unroll
                for (int ni = 0; ni < 8; ni++)
                    acc[mi][ni] = fmaf(a_[mi], b_[ni], acc[mi][ni]);
        }
        __syncthreads();
    }

#pragma unroll
    for (int mi = 0; mi < 4; mi++) {
        const int row = bt0 + tm * 4 + mi;
        float o[8];
#pragma unroll
        for (int ni = 0; ni < 8; ni++) o[ni] = __fadd_rn(acc[mi][ni], bias_r[ni]);
        float4 s0 = {o[0], o[1], o[2], o[3]};
        float4 s1 = {o[4], o[5], o[6], o[7]};
        *(float4*)(dst + (size_t)row * DD + e0 + tn * 8)     = s0;
        *(float4*)(dst + (size_t)row * DD + e0 + tn * 8 + 4) = s1;
    }
}

// ===========================================================================
// Scan: ONE 1024-thread WG per batch (64 WGs). No cross-WG communication.
// Thread (h = tid>>9, e = tid&511) holds Wt[e, h*256 .. h*256+255] in 256
// VGPRs (4 waves/SIMD -> up to 512 VGPRs/wave available). tau lives in LDS;
// per step: [barrier] dot (fp32-peak FMA issue, ~2048 cy/SIMD) [barrier]
// owner reduce+sigmoid+tau publish [barrier] alpha/v/spike tail overlapped
// with next step's dot. Reduction tree replicates the previous verified
// kernel bit-for-bit: per-chunk (a0+a1)+(a2+a3), total (p0+p1)+(p2+p3).
// ===========================================================================
__global__ __launch_bounds__(1024, 1) void scan_kernel(
    const float* __restrict__ tau_w,
    float* __restrict__ xp_sp,          // out base: xp in, spikes out (in-place)
    const float* __restrict__ mm,       // ws: m (B,T,D)
    const float* __restrict__ thrp,
    float* __restrict__ tau_out, float* __restrict__ v_out)
{
    __shared__ __align__(16) float tau_lds[DD];
    __shared__ float partial[DD];

    const int b   = blockIdx.x;
    const int tid = threadIdx.x;
    const int h   = tid >> 9;        // 0: chunks 0,1 (k 0..255); 1: chunks 2,3
    const int e   = tid & 511;
    const bool owner = (h == 0);     // waves 0..7

    // resident weights: Wt[e][h*256 + k], k = 0..255
    float wv[256];
    {
        const f4* wrow = (const f4*)(tau_w + (size_t)e * 1024 + 512 + h * 256);
#pragma unroll
        for (int j = 0; j < 64; j++) {
            f4 t = wrow[j];
            wv[4 * j + 0] = t.x; wv[4 * j + 1] = t.y;
            wv[4 * j + 2] = t.z; wv[4 * j + 3] = t.w;
        }
    }
#pragma unroll
    for (int j = 0; j < 256; j++) asm volatile("" : "+v"(wv[j]));  // keep live

    if (tid < DD) tau_lds[tid] = 1.0f;

    const float thr = thrp[0];
    float v = 0.0f, tau_keep = 1.0f;
    const size_t baseio = (size_t)b * TT * DD + e;

    __syncthreads();

    for (int i = 0; i < TT; i++) {
        // prefetch step inputs (in flight during the dot)
        float xpv = 0.0f, mv = 0.0f;
        if (owner) {
            xpv = xp_sp[baseio + (size_t)i * DD];
            mv  = mm  [baseio + (size_t)i * DD];
        }

        // dot over this thread's 2 chunks c = 2h+cc; tau reads are
        // wave-uniform -> LDS broadcast, conflict-free.
        float q;
        {
            float p0, p1;
#pragma unroll
            for (int cc = 0; cc < 2; cc++) {
                const f4* tl = (const f4*)&tau_lds[(2 * h + cc) * 128];
                float a0 = 0.f, a1 = 0.f, a2 = 0.f, a3 = 0.f;
#pragma unroll
                for (int j = 0; j < 32; j++) {
                    f4 t4 = tl[j];
                    a0 = fmaf(wv[cc * 128 + 4 * j + 0], t4.x, a0);
                    a1 = fmaf(wv[cc * 128 + 4 * j + 1], t4.y, a1);
                    a2 = fmaf(wv[cc * 128 + 4 * j + 2], t4.z, a2);
                    a3 = fmaf(wv[cc * 128 + 4 * j + 3], t4.w, a3);
                }
                float pc = (a0 + a1) + (a2 + a3);
                if (cc == 0) p0 = pc; else p1 = pc;
            }
            q = p0 + p1;   // h=0: P0+P1 ; h=1: P2+P3
        }
        if (!owner) partial[e] = q;
        __syncthreads();   // B: partials visible; all tau reads of step i done

        float tau_n = 0.0f;
        if (owner) {
            float dotv = q + partial[e];          // (P0+P1)+(P2+P3) — exact tree
            float z    = __fadd_rn(xpv, dotv);
            float enz  = expf(-z);
            tau_n      = 1.0f / __fadd_rn(1.0f, enz);
            tau_lds[e] = tau_n;                   // publish FIRST
        }
        __syncthreads();   // A: tau for step i+1 visible

        // tail overlaps next step's dot (non-owner waves already computing)
        if (owner) {
            tau_keep    = tau_n;
            float tpe   = __fadd_rn(tau_n, 1e-6f);
            float alpha = expf(-1.0f / tpe);
            float vn = __fadd_rn(__fmul_rn(alpha, v),
                                 __fmul_rn(__fsub_rn(1.0f, alpha), mv));
            bool s = (vn >= thr);
            xp_sp[baseio + (size_t)i * DD] = s ? 1.0f : 0.0f;
            v = s ? 0.0f : vn;
        }
    }

    if (owner) {
        tau_out[b * DD + e] = tau_keep;
        v_out  [b * DD + e] = v;
    }
}

extern "C" void kernel_launch(void* const* d_in, const int* in_sizes, int n_in,
                              void* d_out, int out_size, void* d_ws, size_t ws_size,
                              hipStream_t stream) {
    (void)in_sizes; (void)n_in; (void)out_size; (void)ws_size;
    const float* x     = (const float*)d_in[0];
    const float* tau_w = (const float*)d_in[1];
    const float* tau_b = (const float*)d_in[2];
    const float* mem_w = (const float*)d_in[3];
    const float* mem_b = (const float*)d_in[4];
    const float* thr   = (const float*)d_in[5];
    float* out = (float*)d_out;

    float* mm = (float*)d_ws;

    gemm_kernel<<<dim3(512, 16), 256, 0, stream>>>(x, tau_w, tau_b, mem_w, mem_b,
                                                   out, mm);
    scan_kernel<<<64, 1024, 0, stream>>>(tau_w, out, mm, thr,
                                         out + (size_t)BT * DD,
                                         out + (size_t)BT * DD + (size_t)BB * DD);
}